// Round 16
// baseline (1469.522 us; speedup 1.0000x reference)
//
#include <hip/hip_runtime.h>
#include <math.h>

#define HDIM 128
#define NIN_ 32
#define RANKS 3

typedef unsigned int u32;
typedef unsigned short u16;
typedef __attribute__((ext_vector_type(8))) short short8;
typedef __attribute__((ext_vector_type(8))) __bf16 bf16x8;
typedef __attribute__((ext_vector_type(4))) float f32x4;

// manual converts (R13-proven: faster than compiler __bf16 casts, -8 VGPR)
__device__ __forceinline__ float bf2f(u16 b) { return __uint_as_float(((u32)b) << 16); }
__device__ __forceinline__ u16 f2bf(float f) {
    u32 u = __float_as_uint(f);
    u32 r = u + 0x7fffu + ((u >> 16) & 1u);
    return (u16)(r >> 16);
}
// fast sigmoid/silu: v_exp_f32 + v_rcp_f32 (~4 VALU ops)
__device__ __forceinline__ float sigmoidf_(float x) {
    return __builtin_amdgcn_rcpf(1.0f + __builtin_amdgcn_exp2f(-1.44269504f * x));
}
__device__ __forceinline__ float siluf_(float x) { return x * sigmoidf_(x); }

template <int SIG>
__device__ __forceinline__ float sigpow(float f) {
#pragma unroll
    for (int q = 0; q < SIG; ++q) f = sigmoidf_(f);
    return f;
}

// ---------------------------------------------------------------------------
__global__ void zero_kernel(u32* __restrict__ p, long long nw) {
    long long i = (long long)blockIdx.x * blockDim.x + threadIdx.x;
    long long stride = (long long)gridDim.x * blockDim.x;
    for (; i < nw; i += stride) p[i] = 0u;
}

// ---------------------------------------------------------------------------
// CSR build (both matrices per launch): histogram -> scan -> cursor fill
// ---------------------------------------------------------------------------
__global__ void count2_kernel(const int* __restrict__ c1, int n1, int* __restrict__ cntA,
                              const int* __restrict__ c2, int n2, int* __restrict__ cntB) {
    int e = blockIdx.x * 256 + threadIdx.x;
    if (e < n1) atomicAdd(&cntA[c1[e]], 1);
    else if (e < n1 + n2) atomicAdd(&cntB[c2[e - n1]], 1);
}

__global__ void fill2_kernel(const int* __restrict__ r1, const int* __restrict__ c1,
                             int* __restrict__ curA, int* __restrict__ esrc1, int n1,
                             const int* __restrict__ r2, const int* __restrict__ c2,
                             int* __restrict__ curB, int* __restrict__ esrc2, int n2) {
    int e = blockIdx.x * 256 + threadIdx.x;
    if (e < n1) {
        int i = atomicAdd(&curA[c1[e]], 1);
        esrc1[i] = r1[e];
    } else if (e < n1 + n2) {
        int ee = e - n1;
        int i = atomicAdd(&curB[c2[ee]], 1);
        esrc2[i] = r2[ee];
    }
}

__global__ void scan1_kernel(const int* __restrict__ cnt, int* __restrict__ bsum, int ndst) {
    __shared__ int lds[256];
    int base = blockIdx.x * 1024, t = threadIdx.x;
    int s = 0;
#pragma unroll
    for (int j = 0; j < 4; ++j) {
        int i = base + t * 4 + j;
        s += (i < ndst) ? cnt[i] : 0;
    }
    lds[t] = s;
    __syncthreads();
    for (int off = 128; off > 0; off >>= 1) {
        if (t < off) lds[t] += lds[t + off];
        __syncthreads();
    }
    if (t == 0) bsum[blockIdx.x] = lds[0];
}

__global__ void scan2_kernel(int* __restrict__ bsum, int nb, int* __restrict__ total) {
    __shared__ int lds[256];
    int t = threadIdx.x;
    int v[8];
    int s = 0;
#pragma unroll
    for (int j = 0; j < 8; ++j) {
        int i = t * 8 + j;
        v[j] = (i < nb) ? bsum[i] : 0;
        s += v[j];
    }
    lds[t] = s;
    __syncthreads();
    for (int off = 1; off < 256; off <<= 1) {
        int y = (t >= off) ? lds[t - off] : 0;
        __syncthreads();
        lds[t] += y;
        __syncthreads();
    }
    int run = lds[t] - s;
#pragma unroll
    for (int j = 0; j < 8; ++j) {
        int i = t * 8 + j;
        if (i < nb) {
            bsum[i] = run;
            run += v[j];
        }
    }
    if (t == 255) *total = run;
}

__global__ void scan3_kernel(const int* __restrict__ cnt, const int* __restrict__ bsum,
                             int* __restrict__ rowptr, int* __restrict__ cursor, int ndst) {
    __shared__ int lds[256];
    int base = blockIdx.x * 1024, t = threadIdx.x;
    int v[4];
    int s = 0;
#pragma unroll
    for (int j = 0; j < 4; ++j) {
        int i = base + t * 4 + j;
        v[j] = (i < ndst) ? cnt[i] : 0;
        s += v[j];
    }
    lds[t] = s;
    __syncthreads();
    for (int off = 1; off < 256; off <<= 1) {
        int y = (t >= off) ? lds[t - off] : 0;
        __syncthreads();
        lds[t] += y;
        __syncthreads();
    }
    int run = bsum[blockIdx.x] + lds[t] - s;
#pragma unroll
    for (int j = 0; j < 4; ++j) {
        int i = base + t * 4 + j;
        if (i < ndst) {
            rowptr[i] = run;
            cursor[i] = run;
            run += v[j];
        }
    }
}

// ---------------------------------------------------------------------------
// Weight pre-transform: plain transposed bf16 (NO swizzle — consumed from
// global via L1/L2, 64B-contiguous per (ct,k0) group):
//   wt[m][col*128 + k] = bf16(W[m][k][col])
// ---------------------------------------------------------------------------
__global__ void wprep_kernel(const float* __restrict__ conv_w, const float* __restrict__ pre_w1,
                             const float* __restrict__ pre_w2, u16* __restrict__ wt, int Lnum) {
    int tid = blockIdx.x * 256 + threadIdx.x;
    int nm = 2 * Lnum + 6;
    if (tid >= nm * 128 * 128) return;
    int m = tid >> 14;
    int r = tid & 16383;
    int k = r >> 7;
    int col = r & 127;
    const float* src;
    if (m < 2 * Lnum) src = conv_w + (size_t)m * 16384;
    else if (m < 2 * Lnum + 3) src = pre_w1 + (size_t)(m - 2 * Lnum) * 16384;
    else src = pre_w2 + (size_t)(m - 2 * Lnum - 3) * 16384;
    float v = src[k * 128 + col];
    wt[(size_t)m * 16384 + col * 128 + k] = f2bf(v);
}

// w_emb^T bf16: wembT[col*32 + k] = bf16(w_emb[k][col])   (8 KB, L2-resident)
__global__ void wembprep_kernel(const float* __restrict__ w_emb, u16* __restrict__ wembT) {
    int tid = blockIdx.x * 256 + threadIdx.x;
    if (tid >= HDIM * NIN_) return;
    int col = tid >> 5, k = tid & 31;
    wembT[col * 32 + k] = f2bf(w_emb[k * HDIM + col]);
}

// ---------------------------------------------------------------------------
// MFMA embed: h = x @ w_emb + b_emb. 512 thr / 8 waves / 128 rows per block.
// ---------------------------------------------------------------------------
__global__ __launch_bounds__(512) void embed_mfma_kernel(const float* __restrict__ x,
                                                         const u16* __restrict__ wembT,
                                                         const float* __restrict__ b,
                                                         u16* __restrict__ h, int n) {
    __shared__ u16 cs[8][16][128];
    const int tid = threadIdx.x;
    const int wave = tid >> 6, lane = tid & 63;
    const int row0 = blockIdx.x * 128;
    const int col = lane & 15, kg = lane >> 4;
    const int wrow0 = row0 + wave * 16;
    const int arow = wrow0 + col;
    const int arowc = arow < n ? arow : (n - 1);

    bf16x8 afrag;
    {
        const float4* xp = (const float4*)(x + (size_t)arowc * NIN_ + kg * 8);
        float4 xa = xp[0], xb = xp[1];
        short8 s;
        s[0] = (short)f2bf(xa.x); s[1] = (short)f2bf(xa.y);
        s[2] = (short)f2bf(xa.z); s[3] = (short)f2bf(xa.w);
        s[4] = (short)f2bf(xb.x); s[5] = (short)f2bf(xb.y);
        s[6] = (short)f2bf(xb.z); s[7] = (short)f2bf(xb.w);
        afrag = __builtin_bit_cast(bf16x8, s);
    }

#pragma unroll
    for (int ct = 0; ct < 8; ++ct) {
        int bcol = ct * 16 + col;
        bf16x8 bfrag = *(const bf16x8*)(wembT + bcol * 32 + kg * 8);
        f32x4 acc = (f32x4){0.f, 0.f, 0.f, 0.f};
        acc = __builtin_amdgcn_mfma_f32_16x16x32_bf16(afrag, bfrag, acc, 0, 0, 0);
        float bv = b[bcol];
#pragma unroll
        for (int r = 0; r < 4; ++r) {
            int crow = kg * 4 + r;
            cs[wave][crow][(ct * 16 + col) ^ ((crow & 7) << 3)] = f2bf(acc[r] + bv);
        }
    }
#pragma unroll
    for (int it = 0; it < 4; ++it) {
        int cid = it * 64 + lane;
        int r = cid >> 4, c = cid & 15;
        int grow = wrow0 + r;
        if (grow < n) {
            short8 v = *(const short8*)(&cs[wave][r][(c * 8) ^ ((r & 7) << 3)]);
            *(short8*)(h + (size_t)grow * HDIM + c * 8) = v;
        }
    }
}

// ---------------------------------------------------------------------------
// GEMM helper: B-frags DIRECT FROM GLOBAL (plain transposed weights; the
// 32KB matrix is L1/L2-resident). No LDS weight buffer, no barriers.
// ---------------------------------------------------------------------------
__device__ __forceinline__ void gemm128g(const bf16x8 afrag[4], const u16* __restrict__ wt,
                                         f32x4 acc[8], int col, int kg) {
#pragma unroll
    for (int ct = 0; ct < 8; ++ct) {
        int bcol = ct * 16 + col;
        const u16* bb = wt + bcol * 128 + kg * 8;
#pragma unroll
        for (int k0 = 0; k0 < 4; ++k0) {
            bf16x8 bfrag = *(const bf16x8*)(bb + k0 * 32);
            acc[ct] = __builtin_amdgcn_mfma_f32_16x16x32_bf16(afrag[k0], bfrag, acc[ct], 0, 0, 0);
        }
    }
}

// pooling of acc (+b2) into p by sorted batch
__device__ __forceinline__ void pool_acc(const f32x4 acc[8], const float* __restrict__ b2,
                                         const int* __restrict__ batch, float* __restrict__ p,
                                         int n, int colOff, int wrow0, int col, int kg) {
    if (wrow0 >= n) return;
    int rend = wrow0 + 15 < n ? wrow0 + 15 : (n - 1);
    int bstart = batch[wrow0];
    int bend = batch[rend];
    if (bstart == bend) {
#pragma unroll
        for (int ct = 0; ct < 8; ++ct) {
            float b2v = b2[ct * 16 + col];
            float s = 0.f;
#pragma unroll
            for (int r = 0; r < 4; ++r) {
                int row = wrow0 + kg * 4 + r;
                if (row < n) s += acc[ct][r] + b2v;
            }
            s += __shfl_xor(s, 16, 64);
            s += __shfl_xor(s, 32, 64);
            if (kg == 0) atomicAdd(&p[bstart * (RANKS * HDIM) + colOff + ct * 16 + col], s);
        }
    } else {
        int bgs[4];
#pragma unroll
        for (int r = 0; r < 4; ++r) {
            int row = wrow0 + kg * 4 + r;
            bgs[r] = (row < n) ? batch[row] : -1;
        }
#pragma unroll
        for (int ct = 0; ct < 8; ++ct) {
            float b2v = b2[ct * 16 + col];
            int curb = -1;
            float cur = 0.f;
#pragma unroll
            for (int r = 0; r < 4; ++r) {
                if (bgs[r] >= 0) {
                    if (bgs[r] != curb) {
                        if (curb >= 0)
                            atomicAdd(&p[curb * (RANKS * HDIM) + colOff + ct * 16 + col], cur);
                        curb = bgs[r];
                        cur = 0.f;
                    }
                    cur += acc[ct][r] + b2v;
                }
            }
            if (curb >= 0) atomicAdd(&p[curb * (RANKS * HDIM) + colOff + ct * 16 + col], cur);
        }
    }
}

// ---------------------------------------------------------------------------
// MERGED rank-1 kernel (L>=2): ONE gather over CSR1 from A, dual f32 accum.
// Barrier-free: zs is wave-local, weights read from global (L1/L2).
// ---------------------------------------------------------------------------
template <int SIGA>
__global__ __launch_bounds__(512) void merged_n1_kernel(
    const u16* __restrict__ srcbuf, const int* __restrict__ rowptr,
    const int* __restrict__ esrc, const u16* __restrict__ wc0, const u16* __restrict__ wc1,
    const u16* __restrict__ w1t, const u16* __restrict__ w2t,
    const float* __restrict__ b1, const float* __restrict__ b2,
    const int* __restrict__ batch, float* __restrict__ p, int colOff,
    u16* __restrict__ outB, int n) {
    __shared__ u16 zs[8][16][128];
    const int tid = threadIdx.x;
    const int wave = tid >> 6, lane = tid & 63;
    const int row0 = blockIdx.x * 128;
    const int col = lane & 15, kg = lane >> 4;
    const int wrow0 = row0 + wave * 16;

    float gr[4][8], gs[4][8];
#pragma unroll
    for (int k0 = 0; k0 < 4; ++k0)
#pragma unroll
        for (int j = 0; j < 8; ++j) { gr[k0][j] = 0.f; gs[k0][j] = 0.f; }

    const int arow = wrow0 + col;
    if (arow < n) {
        int beg = rowptr[arow], end = rowptr[arow + 1];
        for (int e = beg; e < end; e += 2) {
            int s0 = esrc[e];
            bool has1 = (e + 1 < end);
            int s1 = has1 ? esrc[e + 1] : s0;
            const bf16x8* p0 = (const bf16x8*)(srcbuf + (size_t)s0 * HDIM + kg * 8);
            const bf16x8* p1 = (const bf16x8*)(srcbuf + (size_t)s1 * HDIM + kg * 8);
            bf16x8 v0[4], v1[4];
#pragma unroll
            for (int k0 = 0; k0 < 4; ++k0) { v0[k0] = p0[k0 * 4]; v1[k0] = p1[k0 * 4]; }
#pragma unroll
            for (int k0 = 0; k0 < 4; ++k0) {
                short8 sv = __builtin_bit_cast(short8, v0[k0]);
#pragma unroll
                for (int j = 0; j < 8; ++j) {
                    float f = sigpow<SIGA>(bf2f((u16)sv[j]));
                    gr[k0][j] += f;
                    gs[k0][j] += sigmoidf_(f);
                }
            }
            if (has1) {
#pragma unroll
                for (int k0 = 0; k0 < 4; ++k0) {
                    short8 sv = __builtin_bit_cast(short8, v1[k0]);
#pragma unroll
                    for (int j = 0; j < 8; ++j) {
                        float f = sigpow<SIGA>(bf2f((u16)sv[j]));
                        gr[k0][j] += f;
                        gs[k0][j] += sigmoidf_(f);
                    }
                }
            }
        }
    }
    bf16x8 afragR[4], afragS[4];
#pragma unroll
    for (int k0 = 0; k0 < 4; ++k0) {
        short8 sR, sS;
#pragma unroll
        for (int j = 0; j < 8; ++j) {
            sR[j] = (short)f2bf(gr[k0][j]);
            sS[j] = (short)f2bf(gs[k0][j]);
        }
        afragR[k0] = __builtin_bit_cast(bf16x8, sR);
        afragS[k0] = __builtin_bit_cast(bf16x8, sS);
    }

    // ---- B = sigmoid(gr @ Wc0) -> zs (wave-local) -> coalesced store ----
    f32x4 acc[8];
#pragma unroll
    for (int ct = 0; ct < 8; ++ct) acc[ct] = (f32x4){0.f, 0.f, 0.f, 0.f};
    gemm128g(afragR, wc0, acc, col, kg);
#pragma unroll
    for (int ct = 0; ct < 8; ++ct)
#pragma unroll
        for (int r = 0; r < 4; ++r) {
            int crow = kg * 4 + r;
            zs[wave][crow][(ct * 16 + col) ^ ((crow & 7) << 3)] = f2bf(sigmoidf_(acc[ct][r]));
        }
#pragma unroll
    for (int it = 0; it < 4; ++it) {
        int cid = it * 64 + lane;
        int r = cid >> 4, c = cid & 15;
        int grow = wrow0 + r;
        if (grow < n) {
            short8 v = *(const short8*)(&zs[wave][r][(c * 8) ^ ((r & 7) << 3)]);
            *(short8*)(outB + (size_t)grow * HDIM + c * 8) = v;
        }
    }

    // ---- h = sigmoid(gs @ Wc1) -> zs ----
#pragma unroll
    for (int ct = 0; ct < 8; ++ct) acc[ct] = (f32x4){0.f, 0.f, 0.f, 0.f};
    gemm128g(afragS, wc1, acc, col, kg);
#pragma unroll
    for (int ct = 0; ct < 8; ++ct)
#pragma unroll
        for (int r = 0; r < 4; ++r) {
            int crow = kg * 4 + r;
            zs[wave][crow][(ct * 16 + col) ^ ((crow & 7) << 3)] = f2bf(sigmoidf_(acc[ct][r]));
        }

    // ---- z = silu(h @ W1 + b1) ----
    bf16x8 zfrag[4];
    {
        int zswz = (col & 7) << 3;
#pragma unroll
        for (int k0 = 0; k0 < 4; ++k0)
            zfrag[k0] = *(const bf16x8*)(&zs[wave][col][(k0 * 32 + kg * 8) ^ zswz]);
    }
#pragma unroll
    for (int ct = 0; ct < 8; ++ct) acc[ct] = (f32x4){0.f, 0.f, 0.f, 0.f};
    gemm128g(zfrag, w1t, acc, col, kg);
#pragma unroll
    for (int ct = 0; ct < 8; ++ct) {
        float b1v = b1[ct * 16 + col];
#pragma unroll
        for (int r = 0; r < 4; ++r) {
            int crow = kg * 4 + r;
            zs[wave][crow][(ct * 16 + col) ^ ((crow & 7) << 3)] = f2bf(siluf_(acc[ct][r] + b1v));
        }
    }

    // ---- y = z @ W2 -> pool ----
    {
        int zswz = (col & 7) << 3;
#pragma unroll
        for (int k0 = 0; k0 < 4; ++k0)
            zfrag[k0] = *(const bf16x8*)(&zs[wave][col][(k0 * 32 + kg * 8) ^ zswz]);
    }
#pragma unroll
    for (int ct = 0; ct < 8; ++ct) acc[ct] = (f32x4){0.f, 0.f, 0.f, 0.f};
    gemm128g(zfrag, w2t, acc, col, kg);

    pool_acc(acc, b2, batch, p, n, colOff, wrow0, col, kg);
}

// ---------------------------------------------------------------------------
// Fused gather + conv [+ prepool + pool]  (rank 2; rank 1 when L==1)
// Barrier-free, weights from global.
// ---------------------------------------------------------------------------
template <int MODE, int SIG>
__global__ __launch_bounds__(512) void fused_mfma_kernel(
    const u16* __restrict__ srcbuf, const int* __restrict__ rowptr,
    const int* __restrict__ esrc, const u16* __restrict__ wconv,
    const u16* __restrict__ w1t, const u16* __restrict__ w2t,
    const float* __restrict__ b1, const float* __restrict__ b2,
    const int* __restrict__ batch, float* __restrict__ p, int colOff,
    u16* __restrict__ outB, int n) {
    __shared__ u16 zs[8][16][128];
    const int tid = threadIdx.x;
    const int wave = tid >> 6, lane = tid & 63;
    const int row0 = blockIdx.x * 128;
    const int col = lane & 15, kg = lane >> 4;
    const int wrow0 = row0 + wave * 16;

    float ga[4][8];
#pragma unroll
    for (int k0 = 0; k0 < 4; ++k0)
#pragma unroll
        for (int j = 0; j < 8; ++j) ga[k0][j] = 0.f;
    const int arow = wrow0 + col;
    if (arow < n) {
        int beg = rowptr[arow], end = rowptr[arow + 1];
        for (int e = beg; e < end; e += 2) {
            int s0 = esrc[e];
            bool has1 = (e + 1 < end);
            int s1 = has1 ? esrc[e + 1] : s0;
            const bf16x8* p0 = (const bf16x8*)(srcbuf + (size_t)s0 * HDIM + kg * 8);
            const bf16x8* p1 = (const bf16x8*)(srcbuf + (size_t)s1 * HDIM + kg * 8);
            bf16x8 v0[4], v1[4];
#pragma unroll
            for (int k0 = 0; k0 < 4; ++k0) { v0[k0] = p0[k0 * 4]; v1[k0] = p1[k0 * 4]; }
#pragma unroll
            for (int k0 = 0; k0 < 4; ++k0) {
                short8 sv = __builtin_bit_cast(short8, v0[k0]);
#pragma unroll
                for (int j = 0; j < 8; ++j) ga[k0][j] += sigpow<SIG>(bf2f((u16)sv[j]));
            }
            if (has1) {
#pragma unroll
                for (int k0 = 0; k0 < 4; ++k0) {
                    short8 sv = __builtin_bit_cast(short8, v1[k0]);
#pragma unroll
                    for (int j = 0; j < 8; ++j) ga[k0][j] += sigpow<SIG>(bf2f((u16)sv[j]));
                }
            }
        }
    }
    bf16x8 afrag[4];
#pragma unroll
    for (int k0 = 0; k0 < 4; ++k0) {
        short8 s;
#pragma unroll
        for (int j = 0; j < 8; ++j) s[j] = (short)f2bf(ga[k0][j]);
        afrag[k0] = __builtin_bit_cast(bf16x8, s);
    }

    f32x4 acc[8];
#pragma unroll
    for (int ct = 0; ct < 8; ++ct) acc[ct] = (f32x4){0.f, 0.f, 0.f, 0.f};
    gemm128g(afrag, wconv, acc, col, kg);

#pragma unroll
    for (int ct = 0; ct < 8; ++ct)
#pragma unroll
        for (int r = 0; r < 4; ++r) {
            int crow = kg * 4 + r;
            zs[wave][crow][(ct * 16 + col) ^ ((crow & 7) << 3)] = f2bf(sigmoidf_(acc[ct][r]));
        }

    if (MODE == 0) {
#pragma unroll
        for (int it = 0; it < 4; ++it) {
            int cid = it * 64 + lane;
            int r = cid >> 4, c = cid & 15;
            int grow = wrow0 + r;
            if (grow < n) {
                short8 v = *(const short8*)(&zs[wave][r][(c * 8) ^ ((r & 7) << 3)]);
                *(short8*)(outB + (size_t)grow * HDIM + c * 8) = v;
            }
        }
        return;
    }

    bf16x8 zfrag[4];
    {
        int zswz = (col & 7) << 3;
#pragma unroll
        for (int k0 = 0; k0 < 4; ++k0)
            zfrag[k0] = *(const bf16x8*)(&zs[wave][col][(k0 * 32 + kg * 8) ^ zswz]);
    }
#pragma unroll
    for (int ct = 0; ct < 8; ++ct) acc[ct] = (f32x4){0.f, 0.f, 0.f, 0.f};
    gemm128g(zfrag, w1t, acc, col, kg);
#pragma unroll
    for (int ct = 0; ct < 8; ++ct) {
        float b1v = b1[ct * 16 + col];
#pragma unroll
        for (int r = 0; r < 4; ++r) {
            int crow = kg * 4 + r;
            zs[wave][crow][(ct * 16 + col) ^ ((crow & 7) << 3)] = f2bf(siluf_(acc[ct][r] + b1v));
        }
    }

    {
        int zswz = (col & 7) << 3;
#pragma unroll
        for (int k0 = 0; k0 < 4; ++k0)
            zfrag[k0] = *(const bf16x8*)(&zs[wave][col][(k0 * 32 + kg * 8) ^ zswz]);
    }
#pragma unroll
    for (int ct = 0; ct < 8; ++ct) acc[ct] = (f32x4){0.f, 0.f, 0.f, 0.f};
    gemm128g(zfrag, w2t, acc, col, kg);

    pool_acc(acc, b2, batch, p, n, colOff, wrow0, col, kg);
}

// ---------------------------------------------------------------------------
// Rank-0 prepool: y = silu(sig^SIG(h)@W1+b1)@W2+b2, pooled. Barrier-free.
// ---------------------------------------------------------------------------
template <int SIG>
__global__ __launch_bounds__(512) void prepool_mfma_kernel(
    const u16* __restrict__ h, const u16* __restrict__ w1t, const u16* __restrict__ w2t,
    const float* __restrict__ b1, const float* __restrict__ b2, const int* __restrict__ batch,
    float* __restrict__ p, int n, int colOff) {
    __shared__ u16 zs[8][16][128];
    const int tid = threadIdx.x;
    const int wave = tid >> 6, lane = tid & 63;
    const int row0 = blockIdx.x * 128;
    const int col = lane & 15, kg = lane >> 4;
    const int wrow0 = row0 + wave * 16;

    const int arow = wrow0 + col;
    const int arowc = arow < n ? arow : (n - 1);
    bf16x8 afrag[4];
    {
        const bf16x8* ap = (const bf16x8*)(h + (size_t)arowc * HDIM + kg * 8);
#pragma unroll
        for (int k0 = 0; k0 < 4; ++k0) afrag[k0] = ap[k0 * 4];
    }
    if (SIG > 0) {
#pragma unroll
        for (int k0 = 0; k0 < 4; ++k0) {
            short8 s = __builtin_bit_cast(short8, afrag[k0]);
#pragma unroll
            for (int j = 0; j < 8; ++j) s[j] = (short)f2bf(sigpow<SIG>(bf2f((u16)s[j])));
            afrag[k0] = __builtin_bit_cast(bf16x8, s);
        }
    }

    f32x4 acc[8];
#pragma unroll
    for (int ct = 0; ct < 8; ++ct) acc[ct] = (f32x4){0.f, 0.f, 0.f, 0.f};
    gemm128g(afrag, w1t, acc, col, kg);
#pragma unroll
    for (int ct = 0; ct < 8; ++ct) {
        float b1v = b1[ct * 16 + col];
#pragma unroll
        for (int r = 0; r < 4; ++r) {
            int crow = kg * 4 + r;
            zs[wave][crow][(ct * 16 + col) ^ ((crow & 7) << 3)] = f2bf(siluf_(acc[ct][r] + b1v));
        }
    }

    bf16x8 zfrag[4];
    {
        int zswz = (col & 7) << 3;
#pragma unroll
        for (int k0 = 0; k0 < 4; ++k0)
            zfrag[k0] = *(const bf16x8*)(&zs[wave][col][(k0 * 32 + kg * 8) ^ zswz]);
    }
#pragma unroll
    for (int ct = 0; ct < 8; ++ct) acc[ct] = (f32x4){0.f, 0.f, 0.f, 0.f};
    gemm128g(zfrag, w2t, acc, col, kg);

    pool_acc(acc, b2, batch, p, n, colOff, wrow0, col, kg);
}

// ---------------------------------------------------------------------------
__global__ void final_kernel(const float* __restrict__ p, const float* __restrict__ w1,
                             const float* __restrict__ b1, const float* __restrict__ w2,
                             const float* __restrict__ b2, float* __restrict__ out) {
    const int g = blockIdx.x;
    const int c = threadIdx.x;
    const float* pg = p + g * (RANKS * HDIM);
    float acc = b1[c];
    for (int k = 0; k < RANKS * HDIM; ++k) acc = fmaf(pg[k], w1[k * HDIM + c], acc);
    float z = siluf_(acc);
    float v = z * w2[c];
#pragma unroll
    for (int off = 32; off > 0; off >>= 1) v += __shfl_down(v, off, 64);
    __shared__ float red[2];
    if ((c & 63) == 0) red[c >> 6] = v;
    __syncthreads();
    if (c == 0) out[g] = red[0] + red[1] + b2[0];
}

// ---------------------------------------------------------------------------
extern "C" void kernel_launch(void* const* d_in, const int* in_sizes, int n_in,
                              void* d_out, int out_size, void* d_ws, size_t ws_size,
                              hipStream_t stream) {
    const float* x0 = (const float*)d_in[0];
    const float* x1 = (const float*)d_in[1];
    const int* b1_rows = (const int*)d_in[3];
    const int* b1_cols = (const int*)d_in[4];
    const int* b2_rows = (const int*)d_in[5];
    const int* b2_cols = (const int*)d_in[6];
    const int* batch0 = (const int*)d_in[7];
    const int* batch1 = (const int*)d_in[8];
    const int* batch2 = (const int*)d_in[9];
    const float* w_emb = (const float*)d_in[10];
    const float* b_emb = (const float*)d_in[11];
    const float* conv_w = (const float*)d_in[12];
    const float* pre_w1 = (const float*)d_in[13];
    const float* pre_b1 = (const float*)d_in[14];
    const float* pre_w2 = (const float*)d_in[15];
    const float* pre_b2 = (const float*)d_in[16];
    const float* post_w1 = (const float*)d_in[17];
    const float* post_b1 = (const float*)d_in[18];
    const float* post_w2 = (const float*)d_in[19];
    const float* post_b2 = (const float*)d_in[20];

    const int N0 = in_sizes[0] / NIN_;
    const int N1 = in_sizes[1] / NIN_;
    const int N2 = in_sizes[2] / NIN_;
    const int NNZ1 = in_sizes[3];
    const int NNZ2 = in_sizes[5];
    const int L = in_sizes[12] / (2 * HDIM * HDIM);
    const int Gn = out_size;

    // ws: A | B | p | wt | wembT | CSR   (~228 MB, < 293.7 MB proven bound)
    u16* A = (u16*)d_ws;
    u16* B = A + (size_t)N0 * HDIM;
    float* p = (float*)(B + (size_t)N1 * HDIM);
    u16* wt = (u16*)(p + (size_t)Gn * RANKS * HDIM);
    const u16* wt_conv = wt;                        // [2L][16384]
    const u16* wt_p1 = wt + (size_t)2 * L * 16384;  // [3][16384]
    const u16* wt_p2 = wt_p1 + (size_t)3 * 16384;   // [3][16384]
    u16* wembT = wt + (size_t)(2 * L + 6) * 16384;  // [4096]
    int* ip = (int*)(wembT + 4096);
    int* rowptr1 = ip;  ip += N1 + 1;
    int* rowptr2 = ip;  ip += N2 + 1;
    int* esrc1 = ip;    ip += NNZ1;
    int* esrc2 = ip;    ip += NNZ2;
    int* cntA = ip;     ip += N1;
    int* cntB = ip;     ip += N2;
    int* curA = ip;     ip += N1;
    int* curB = ip;     ip += N2;
    int* bsum = ip;     ip += 2048;

    // 0) weight pre-transforms + CSR builds
    {
        int tot = (2 * L + 6) * 16384;
        wprep_kernel<<<(tot + 255) / 256, 256, 0, stream>>>(conv_w, pre_w1, pre_w2, wt, L);
        wembprep_kernel<<<16, 256, 0, stream>>>(w_emb, wembT);

        zero_kernel<<<1024, 256, 0, stream>>>((u32*)cntA, (long long)(N1 + N2));
        count2_kernel<<<(NNZ1 + NNZ2 + 255) / 256, 256, 0, stream>>>(b1_cols, NNZ1, cntA,
                                                                     b2_cols, NNZ2, cntB);
        int nb1 = (N1 + 1023) / 1024;
        scan1_kernel<<<nb1, 256, 0, stream>>>(cntA, bsum, N1);
        scan2_kernel<<<1, 256, 0, stream>>>(bsum, nb1, rowptr1 + N1);
        scan3_kernel<<<nb1, 256, 0, stream>>>(cntA, bsum, rowptr1, curA, N1);
        int nb2 = (N2 + 1023) / 1024;
        scan1_kernel<<<nb2, 256, 0, stream>>>(cntB, bsum, N2);
        scan2_kernel<<<1, 256, 0, stream>>>(bsum, nb2, rowptr2 + N2);
        scan3_kernel<<<nb2, 256, 0, stream>>>(cntB, bsum, rowptr2, curB, N2);
        fill2_kernel<<<(NNZ1 + NNZ2 + 255) / 256, 256, 0, stream>>>(
            b1_rows, b1_cols, curA, esrc1, NNZ1, b2_rows, b2_cols, curB, esrc2, NNZ2);
    }

    // 1) rank-0 embedding into A (raw; sigmoids applied lazily downstream)
    embed_mfma_kernel<<<(N0 + 127) / 128, 512, 0, stream>>>(x0, wembT, b_emb, A, N0);

    // 2) pooled state buffer
    zero_kernel<<<64, 256, 0, stream>>>((u32*)p, (long long)Gn * RANKS * HDIM);

    if (L >= 2) {
        // MERGED: one CSR1 gather -> {B store, rank-1 prepool -> pool}
        int grid = (N1 + 127) / 128;
        const u16* wc0 = wt_conv + (size_t)((L - 2) * 2 + 0) * 16384;
        const u16* wc1 = wt_conv + (size_t)((L - 1) * 2 + 0) * 16384;
        switch (L - 2) {
            case 0: merged_n1_kernel<0><<<grid, 512, 0, stream>>>(
                        A, rowptr1, esrc1, wc0, wc1, wt_p1 + 16384, wt_p2 + 16384,
                        pre_b1 + HDIM, pre_b2 + HDIM, batch1, p, HDIM, B, N1); break;
            case 1: merged_n1_kernel<1><<<grid, 512, 0, stream>>>(
                        A, rowptr1, esrc1, wc0, wc1, wt_p1 + 16384, wt_p2 + 16384,
                        pre_b1 + HDIM, pre_b2 + HDIM, batch1, p, HDIM, B, N1); break;
            default: merged_n1_kernel<2><<<grid, 512, 0, stream>>>(
                        A, rowptr1, esrc1, wc0, wc1, wt_p1 + 16384, wt_p2 + 16384,
                        pre_b1 + HDIM, pre_b2 + HDIM, batch1, p, HDIM, B, N1); break;
        }
    } else {
        embed_mfma_kernel<<<(N1 + 127) / 128, 512, 0, stream>>>(x1, wembT, b_emb, B, N1);
        fused_mfma_kernel<1, 0><<<(N1 + 127) / 128, 512, 0, stream>>>(
            A, rowptr1, esrc1, wt_conv, wt_p1 + 16384, wt_p2 + 16384,
            pre_b1 + HDIM, pre_b2 + HDIM, batch1, p, HDIM, nullptr, N1);
    }

    // rank 2: gather(B over CSR2) -> conv[L-1,1] -> prepool[2] -> pool
    fused_mfma_kernel<1, 0><<<(N2 + 127) / 128, 512, 0, stream>>>(
        B, rowptr2, esrc2, wt_conv + (size_t)((L - 1) * 2 + 1) * 16384,
        wt_p1 + 2 * 16384, wt_p2 + 2 * 16384, pre_b1 + 2 * HDIM, pre_b2 + 2 * HDIM,
        batch2, p, 2 * HDIM, nullptr, N2);

    // rank 0: sig^L(A) -> prepool[0] -> pool
    {
        int grid = (N0 + 127) / 128;
        switch (L) {
            case 1: prepool_mfma_kernel<1><<<grid, 512, 0, stream>>>(
                        A, wt_p1, wt_p2, pre_b1, pre_b2, batch0, p, N0, 0); break;
            case 2: prepool_mfma_kernel<2><<<grid, 512, 0, stream>>>(
                        A, wt_p1, wt_p2, pre_b1, pre_b2, batch0, p, N0, 0); break;
            default: prepool_mfma_kernel<3><<<grid, 512, 0, stream>>>(
                        A, wt_p1, wt_p2, pre_b1, pre_b2, batch0, p, N0, 0); break;
        }
    }

    // 4) head
    final_kernel<<<Gn, HDIM, 0, stream>>>(p, post_w1, post_b1, post_w2, post_b2, (float*)d_out);
}

// Round 17
// 767.127 us; speedup vs baseline: 1.9156x; 1.9156x over previous
//
#include <hip/hip_runtime.h>
#include <math.h>

#define HDIM 128
#define NIN_ 32
#define RANKS 3

typedef unsigned int u32;
typedef unsigned short u16;
typedef __attribute__((ext_vector_type(8))) short short8;
typedef __attribute__((ext_vector_type(8))) __bf16 bf16x8;
typedef __attribute__((ext_vector_type(4))) float f32x4;

// manual converts (R13-proven)
__device__ __forceinline__ float bf2f(u16 b) { return __uint_as_float(((u32)b) << 16); }
__device__ __forceinline__ u16 f2bf(float f) {
    u32 u = __float_as_uint(f);
    u32 r = u + 0x7fffu + ((u >> 16) & 1u);
    return (u16)(r >> 16);
}
__device__ __forceinline__ float sigmoidf_(float x) {
    return __builtin_amdgcn_rcpf(1.0f + __builtin_amdgcn_exp2f(-1.44269504f * x));
}
__device__ __forceinline__ float siluf_(float x) { return x * sigmoidf_(x); }

template <int SIG>
__device__ __forceinline__ float sigpow(float f) {
#pragma unroll
    for (int q = 0; q < SIG; ++q) f = sigmoidf_(f);
    return f;
}

// ---------------------------------------------------------------------------
__global__ void zero_kernel(u32* __restrict__ p, long long nw) {
    long long i = (long long)blockIdx.x * blockDim.x + threadIdx.x;
    long long stride = (long long)gridDim.x * blockDim.x;
    for (; i < nw; i += stride) p[i] = 0u;
}

// ---------------------------------------------------------------------------
// CSR build (both matrices per launch): histogram -> scan -> cursor fill
// ---------------------------------------------------------------------------
__global__ void count2_kernel(const int* __restrict__ c1, int n1, int* __restrict__ cntA,
                              const int* __restrict__ c2, int n2, int* __restrict__ cntB) {
    int e = blockIdx.x * 256 + threadIdx.x;
    if (e < n1) atomicAdd(&cntA[c1[e]], 1);
    else if (e < n1 + n2) atomicAdd(&cntB[c2[e - n1]], 1);
}

__global__ void fill2_kernel(const int* __restrict__ r1, const int* __restrict__ c1,
                             int* __restrict__ curA, int* __restrict__ esrc1, int n1,
                             const int* __restrict__ r2, const int* __restrict__ c2,
                             int* __restrict__ curB, int* __restrict__ esrc2, int n2) {
    int e = blockIdx.x * 256 + threadIdx.x;
    if (e < n1) {
        int i = atomicAdd(&curA[c1[e]], 1);
        esrc1[i] = r1[e];
    } else if (e < n1 + n2) {
        int ee = e - n1;
        int i = atomicAdd(&curB[c2[ee]], 1);
        esrc2[i] = r2[ee];
    }
}

__global__ void scan1_kernel(const int* __restrict__ cnt, int* __restrict__ bsum, int ndst) {
    __shared__ int lds[256];
    int base = blockIdx.x * 1024, t = threadIdx.x;
    int s = 0;
#pragma unroll
    for (int j = 0; j < 4; ++j) {
        int i = base + t * 4 + j;
        s += (i < ndst) ? cnt[i] : 0;
    }
    lds[t] = s;
    __syncthreads();
    for (int off = 128; off > 0; off >>= 1) {
        if (t < off) lds[t] += lds[t + off];
        __syncthreads();
    }
    if (t == 0) bsum[blockIdx.x] = lds[0];
}

__global__ void scan2_kernel(int* __restrict__ bsum, int nb, int* __restrict__ total) {
    __shared__ int lds[256];
    int t = threadIdx.x;
    int v[8];
    int s = 0;
#pragma unroll
    for (int j = 0; j < 8; ++j) {
        int i = t * 8 + j;
        v[j] = (i < nb) ? bsum[i] : 0;
        s += v[j];
    }
    lds[t] = s;
    __syncthreads();
    for (int off = 1; off < 256; off <<= 1) {
        int y = (t >= off) ? lds[t - off] : 0;
        __syncthreads();
        lds[t] += y;
        __syncthreads();
    }
    int run = lds[t] - s;
#pragma unroll
    for (int j = 0; j < 8; ++j) {
        int i = t * 8 + j;
        if (i < nb) {
            bsum[i] = run;
            run += v[j];
        }
    }
    if (t == 255) *total = run;
}

__global__ void scan3_kernel(const int* __restrict__ cnt, const int* __restrict__ bsum,
                             int* __restrict__ rowptr, int* __restrict__ cursor, int ndst) {
    __shared__ int lds[256];
    int base = blockIdx.x * 1024, t = threadIdx.x;
    int v[4];
    int s = 0;
#pragma unroll
    for (int j = 0; j < 4; ++j) {
        int i = base + t * 4 + j;
        v[j] = (i < ndst) ? cnt[i] : 0;
        s += v[j];
    }
    lds[t] = s;
    __syncthreads();
    for (int off = 1; off < 256; off <<= 1) {
        int y = (t >= off) ? lds[t - off] : 0;
        __syncthreads();
        lds[t] += y;
        __syncthreads();
    }
    int run = bsum[blockIdx.x] + lds[t] - s;
#pragma unroll
    for (int j = 0; j < 4; ++j) {
        int i = base + t * 4 + j;
        if (i < ndst) {
            rowptr[i] = run;
            cursor[i] = run;
            run += v[j];
        }
    }
}

// ---------------------------------------------------------------------------
// Weight pre-transform: wt[m][col*128 + (k ^ ((col&7)<<3))] = bf16(W[m][k][col])
// ---------------------------------------------------------------------------
__global__ void wprep_kernel(const float* __restrict__ conv_w, const float* __restrict__ pre_w1,
                             const float* __restrict__ pre_w2, u16* __restrict__ wt, int Lnum) {
    int tid = blockIdx.x * 256 + threadIdx.x;
    int nm = 2 * Lnum + 6;
    if (tid >= nm * 128 * 128) return;
    int m = tid >> 14;
    int r = tid & 16383;
    int k = r >> 7;
    int col = r & 127;
    const float* src;
    if (m < 2 * Lnum) src = conv_w + (size_t)m * 16384;
    else if (m < 2 * Lnum + 3) src = pre_w1 + (size_t)(m - 2 * Lnum) * 16384;
    else src = pre_w2 + (size_t)(m - 2 * Lnum - 3) * 16384;
    float v = src[k * 128 + col];
    wt[(size_t)m * 16384 + col * 128 + (k ^ ((col & 7) << 3))] = f2bf(v);
}

// w_emb^T bf16: wembT[col*32 + k] = bf16(w_emb[k][col])
__global__ void wembprep_kernel(const float* __restrict__ w_emb, u16* __restrict__ wembT) {
    int tid = blockIdx.x * 256 + threadIdx.x;
    if (tid >= HDIM * NIN_) return;
    int col = tid >> 5, k = tid & 31;
    wembT[col * 32 + k] = f2bf(w_emb[k * HDIM + col]);
}

// ---------------------------------------------------------------------------
// MFMA embed: h = x @ w_emb + b_emb; optionally hs = sigmoid(h).
// ---------------------------------------------------------------------------
__global__ __launch_bounds__(512) void embed_mfma_kernel(const float* __restrict__ x,
                                                         const u16* __restrict__ wembT,
                                                         const float* __restrict__ b,
                                                         u16* __restrict__ h,
                                                         u16* __restrict__ hs, int n) {
    __shared__ u16 cs[8][16][128];
    const int tid = threadIdx.x;
    const int wave = tid >> 6, lane = tid & 63;
    const int row0 = blockIdx.x * 128;
    const int col = lane & 15, kg = lane >> 4;
    const int wrow0 = row0 + wave * 16;
    const int arow = wrow0 + col;
    const int arowc = arow < n ? arow : (n - 1);

    bf16x8 afrag;
    {
        const float4* xp = (const float4*)(x + (size_t)arowc * NIN_ + kg * 8);
        float4 xa = xp[0], xb = xp[1];
        short8 s;
        s[0] = (short)f2bf(xa.x); s[1] = (short)f2bf(xa.y);
        s[2] = (short)f2bf(xa.z); s[3] = (short)f2bf(xa.w);
        s[4] = (short)f2bf(xb.x); s[5] = (short)f2bf(xb.y);
        s[6] = (short)f2bf(xb.z); s[7] = (short)f2bf(xb.w);
        afrag = __builtin_bit_cast(bf16x8, s);
    }

    f32x4 accs[8];
#pragma unroll
    for (int ct = 0; ct < 8; ++ct) {
        int bcol = ct * 16 + col;
        bf16x8 bfrag = *(const bf16x8*)(wembT + bcol * 32 + kg * 8);
        f32x4 acc = (f32x4){0.f, 0.f, 0.f, 0.f};
        acc = __builtin_amdgcn_mfma_f32_16x16x32_bf16(afrag, bfrag, acc, 0, 0, 0);
        float bv = b[bcol];
#pragma unroll
        for (int r = 0; r < 4; ++r) acc[r] += bv;
        accs[ct] = acc;
#pragma unroll
        for (int r = 0; r < 4; ++r) {
            int crow = kg * 4 + r;
            cs[wave][crow][(ct * 16 + col) ^ ((crow & 7) << 3)] = f2bf(acc[r]);
        }
    }
#pragma unroll
    for (int it = 0; it < 4; ++it) {
        int cid = it * 64 + lane;
        int r = cid >> 4, c = cid & 15;
        int grow = wrow0 + r;
        if (grow < n) {
            short8 v = *(const short8*)(&cs[wave][r][(c * 8) ^ ((r & 7) << 3)]);
            *(short8*)(h + (size_t)grow * HDIM + c * 8) = v;
        }
    }
    if (hs) {
        // second epilogue pass: sigmoid (wave-local LDS reuse)
#pragma unroll
        for (int ct = 0; ct < 8; ++ct)
#pragma unroll
            for (int r = 0; r < 4; ++r) {
                int crow = kg * 4 + r;
                cs[wave][crow][(ct * 16 + col) ^ ((crow & 7) << 3)] = f2bf(sigmoidf_(accs[ct][r]));
            }
#pragma unroll
        for (int it = 0; it < 4; ++it) {
            int cid = it * 64 + lane;
            int r = cid >> 4, c = cid & 15;
            int grow = wrow0 + r;
            if (grow < n) {
                short8 v = *(const short8*)(&cs[wave][r][(c * 8) ^ ((r & 7) << 3)]);
                *(short8*)(hs + (size_t)grow * HDIM + c * 8) = v;
            }
        }
    }
}

// ---------------------------------------------------------------------------
// GEMM helper (swizzled LDS weights) + staging
// ---------------------------------------------------------------------------
__device__ __forceinline__ void gemm128(const bf16x8 afrag[4], const u16* wls, f32x4 acc[8],
                                        int col, int kg) {
#pragma unroll
    for (int ct = 0; ct < 8; ++ct) {
        int bcol = ct * 16 + col;
        const u16* bb = wls + bcol * 128;
        int swz = (bcol & 7) << 3;
#pragma unroll
        for (int k0 = 0; k0 < 4; ++k0) {
            bf16x8 bfrag = *(const bf16x8*)(bb + ((k0 * 32 + kg * 8) ^ swz));
            acc[ct] = __builtin_amdgcn_mfma_f32_16x16x32_bf16(afrag[k0], bfrag, acc[ct], 0, 0, 0);
        }
    }
}

__device__ __forceinline__ void stage_w(const u16* __restrict__ w, u16* wls, int tid) {
    const uint4* g = (const uint4*)w;
    uint4* l = (uint4*)wls;
#pragma unroll
    for (int i = 0; i < 4; ++i) l[tid + i * 512] = g[tid + i * 512];
}

// pooling of acc (+b2) into p by sorted batch
__device__ __forceinline__ void pool_acc(const f32x4 acc[8], const float* __restrict__ b2,
                                         const int* __restrict__ batch, float* __restrict__ p,
                                         int n, int colOff, int wrow0, int col, int kg) {
    if (wrow0 >= n) return;
    int rend = wrow0 + 15 < n ? wrow0 + 15 : (n - 1);
    int bstart = batch[wrow0];
    int bend = batch[rend];
    if (bstart == bend) {
#pragma unroll
        for (int ct = 0; ct < 8; ++ct) {
            float b2v = b2[ct * 16 + col];
            float s = 0.f;
#pragma unroll
            for (int r = 0; r < 4; ++r) {
                int row = wrow0 + kg * 4 + r;
                if (row < n) s += acc[ct][r] + b2v;
            }
            s += __shfl_xor(s, 16, 64);
            s += __shfl_xor(s, 32, 64);
            if (kg == 0) atomicAdd(&p[bstart * (RANKS * HDIM) + colOff + ct * 16 + col], s);
        }
    } else {
        int bgs[4];
#pragma unroll
        for (int r = 0; r < 4; ++r) {
            int row = wrow0 + kg * 4 + r;
            bgs[r] = (row < n) ? batch[row] : -1;
        }
#pragma unroll
        for (int ct = 0; ct < 8; ++ct) {
            float b2v = b2[ct * 16 + col];
            int curb = -1;
            float cur = 0.f;
#pragma unroll
            for (int r = 0; r < 4; ++r) {
                if (bgs[r] >= 0) {
                    if (bgs[r] != curb) {
                        if (curb >= 0)
                            atomicAdd(&p[curb * (RANKS * HDIM) + colOff + ct * 16 + col], cur);
                        curb = bgs[r];
                        cur = 0.f;
                    }
                    cur += acc[ct][r] + b2v;
                }
            }
            if (curb >= 0) atomicAdd(&p[curb * (RANKS * HDIM) + colOff + ct * 16 + col], cur);
        }
    }
}

// ---------------------------------------------------------------------------
// MERGED rank-1 kernel (L>=2): ONE gather over CSR1, dual f32 accum.
// SIGA==0 (L==2): dual-stream pure-add gather from srcA (raw) + srcS (sigmoid)
//   — no transcendentals in the edge loop (they were hoisted into embed).
// SIGA>0: generic single-stream path with sigpow (reads srcA).
// ---------------------------------------------------------------------------
template <int SIGA>
__global__ __launch_bounds__(512) void merged_n1_kernel(
    const u16* __restrict__ srcA, const u16* __restrict__ srcS,
    const int* __restrict__ rowptr, const int* __restrict__ esrc,
    const u16* __restrict__ wc0, const u16* __restrict__ wc1,
    const u16* __restrict__ w1t, const u16* __restrict__ w2t,
    const float* __restrict__ b1, const float* __restrict__ b2,
    const int* __restrict__ batch, float* __restrict__ p, int colOff,
    u16* __restrict__ outB, int n) {
    __shared__ u16 wls[16384];
    __shared__ u16 zs[8][16][128];
    const int tid = threadIdx.x;
    const int wave = tid >> 6, lane = tid & 63;
    const int row0 = blockIdx.x * 128;
    const int col = lane & 15, kg = lane >> 4;
    const int wrow0 = row0 + wave * 16;

    stage_w(wc0, wls, tid);

    float gr[4][8], gs[4][8];
#pragma unroll
    for (int k0 = 0; k0 < 4; ++k0)
#pragma unroll
        for (int j = 0; j < 8; ++j) { gr[k0][j] = 0.f; gs[k0][j] = 0.f; }

    const int arow = wrow0 + col;
    if (arow < n) {
        int beg = rowptr[arow], end = rowptr[arow + 1];
        if constexpr (SIGA == 0) {
            for (int e = beg; e < end; ++e) {
                int s0 = esrc[e];
                const bf16x8* pa = (const bf16x8*)(srcA + (size_t)s0 * HDIM + kg * 8);
                const bf16x8* ps = (const bf16x8*)(srcS + (size_t)s0 * HDIM + kg * 8);
                bf16x8 va[4], vs[4];
#pragma unroll
                for (int k0 = 0; k0 < 4; ++k0) { va[k0] = pa[k0 * 4]; vs[k0] = ps[k0 * 4]; }
#pragma unroll
                for (int k0 = 0; k0 < 4; ++k0) {
                    short8 a = __builtin_bit_cast(short8, va[k0]);
                    short8 s = __builtin_bit_cast(short8, vs[k0]);
#pragma unroll
                    for (int j = 0; j < 8; ++j) {
                        gr[k0][j] += bf2f((u16)a[j]);
                        gs[k0][j] += bf2f((u16)s[j]);
                    }
                }
            }
        } else {
            for (int e = beg; e < end; e += 2) {
                int s0 = esrc[e];
                bool has1 = (e + 1 < end);
                int s1 = has1 ? esrc[e + 1] : s0;
                const bf16x8* p0 = (const bf16x8*)(srcA + (size_t)s0 * HDIM + kg * 8);
                const bf16x8* p1 = (const bf16x8*)(srcA + (size_t)s1 * HDIM + kg * 8);
                bf16x8 v0[4], v1[4];
#pragma unroll
                for (int k0 = 0; k0 < 4; ++k0) { v0[k0] = p0[k0 * 4]; v1[k0] = p1[k0 * 4]; }
#pragma unroll
                for (int k0 = 0; k0 < 4; ++k0) {
                    short8 sv = __builtin_bit_cast(short8, v0[k0]);
#pragma unroll
                    for (int j = 0; j < 8; ++j) {
                        float f = sigpow<SIGA>(bf2f((u16)sv[j]));
                        gr[k0][j] += f;
                        gs[k0][j] += sigmoidf_(f);
                    }
                }
                if (has1) {
#pragma unroll
                    for (int k0 = 0; k0 < 4; ++k0) {
                        short8 sv = __builtin_bit_cast(short8, v1[k0]);
#pragma unroll
                        for (int j = 0; j < 8; ++j) {
                            float f = sigpow<SIGA>(bf2f((u16)sv[j]));
                            gr[k0][j] += f;
                            gs[k0][j] += sigmoidf_(f);
                        }
                    }
                }
            }
        }
    }
    bf16x8 afragR[4], afragS[4];
#pragma unroll
    for (int k0 = 0; k0 < 4; ++k0) {
        short8 sR, sS;
#pragma unroll
        for (int j = 0; j < 8; ++j) {
            sR[j] = (short)f2bf(gr[k0][j]);
            sS[j] = (short)f2bf(gs[k0][j]);
        }
        afragR[k0] = __builtin_bit_cast(bf16x8, sR);
        afragS[k0] = __builtin_bit_cast(bf16x8, sS);
    }
    __syncthreads();  // wls (Wc0) ready

    // ---- B = sigmoid(gr @ Wc0) -> zs -> coalesced store ----
    f32x4 acc[8];
#pragma unroll
    for (int ct = 0; ct < 8; ++ct) acc[ct] = (f32x4){0.f, 0.f, 0.f, 0.f};
    gemm128(afragR, wls, acc, col, kg);
#pragma unroll
    for (int ct = 0; ct < 8; ++ct)
#pragma unroll
        for (int r = 0; r < 4; ++r) {
            int crow = kg * 4 + r;
            zs[wave][crow][(ct * 16 + col) ^ ((crow & 7) << 3)] = f2bf(sigmoidf_(acc[ct][r]));
        }
#pragma unroll
    for (int it = 0; it < 4; ++it) {
        int cid = it * 64 + lane;
        int r = cid >> 4, c = cid & 15;
        int grow = wrow0 + r;
        if (grow < n) {
            short8 v = *(const short8*)(&zs[wave][r][(c * 8) ^ ((r & 7) << 3)]);
            *(short8*)(outB + (size_t)grow * HDIM + c * 8) = v;
        }
    }

    __syncthreads();
    stage_w(wc1, wls, tid);
    __syncthreads();

    // ---- h = sigmoid(gs @ Wc1) -> zs ----
#pragma unroll
    for (int ct = 0; ct < 8; ++ct) acc[ct] = (f32x4){0.f, 0.f, 0.f, 0.f};
    gemm128(afragS, wls, acc, col, kg);
#pragma unroll
    for (int ct = 0; ct < 8; ++ct)
#pragma unroll
        for (int r = 0; r < 4; ++r) {
            int crow = kg * 4 + r;
            zs[wave][crow][(ct * 16 + col) ^ ((crow & 7) << 3)] = f2bf(sigmoidf_(acc[ct][r]));
        }
    __syncthreads();
    stage_w(w1t, wls, tid);
    __syncthreads();

    // ---- z = silu(h @ W1 + b1) ----
    bf16x8 zfrag[4];
    {
        int zswz = (col & 7) << 3;
#pragma unroll
        for (int k0 = 0; k0 < 4; ++k0)
            zfrag[k0] = *(const bf16x8*)(&zs[wave][col][(k0 * 32 + kg * 8) ^ zswz]);
    }
#pragma unroll
    for (int ct = 0; ct < 8; ++ct) acc[ct] = (f32x4){0.f, 0.f, 0.f, 0.f};
    gemm128(zfrag, wls, acc, col, kg);
#pragma unroll
    for (int ct = 0; ct < 8; ++ct) {
        float b1v = b1[ct * 16 + col];
#pragma unroll
        for (int r = 0; r < 4; ++r) {
            int crow = kg * 4 + r;
            zs[wave][crow][(ct * 16 + col) ^ ((crow & 7) << 3)] = f2bf(siluf_(acc[ct][r] + b1v));
        }
    }
    __syncthreads();
    stage_w(w2t, wls, tid);
    __syncthreads();

    // ---- y = z @ W2 -> pool ----
    {
        int zswz = (col & 7) << 3;
#pragma unroll
        for (int k0 = 0; k0 < 4; ++k0)
            zfrag[k0] = *(const bf16x8*)(&zs[wave][col][(k0 * 32 + kg * 8) ^ zswz]);
    }
#pragma unroll
    for (int ct = 0; ct < 8; ++ct) acc[ct] = (f32x4){0.f, 0.f, 0.f, 0.f};
    gemm128(zfrag, wls, acc, col, kg);

    pool_acc(acc, b2, batch, p, n, colOff, wrow0, col, kg);
}

// ---------------------------------------------------------------------------
// Fused gather + conv [+ prepool + pool]  (rank 2; rank 1 when L==1)
// ---------------------------------------------------------------------------
template <int MODE, int SIG>
__global__ __launch_bounds__(512) void fused_mfma_kernel(
    const u16* __restrict__ srcbuf, const int* __restrict__ rowptr,
    const int* __restrict__ esrc, const u16* __restrict__ wconv,
    const u16* __restrict__ w1t, const u16* __restrict__ w2t,
    const float* __restrict__ b1, const float* __restrict__ b2,
    const int* __restrict__ batch, float* __restrict__ p, int colOff,
    u16* __restrict__ outB, int n) {
    __shared__ u16 wls[16384];
    __shared__ u16 zs[8][16][128];
    const int tid = threadIdx.x;
    const int wave = tid >> 6, lane = tid & 63;
    const int row0 = blockIdx.x * 128;
    const int col = lane & 15, kg = lane >> 4;
    const int wrow0 = row0 + wave * 16;

    stage_w(wconv, wls, tid);

    float ga[4][8];
#pragma unroll
    for (int k0 = 0; k0 < 4; ++k0)
#pragma unroll
        for (int j = 0; j < 8; ++j) ga[k0][j] = 0.f;
    const int arow = wrow0 + col;
    if (arow < n) {
        int beg = rowptr[arow], end = rowptr[arow + 1];
        for (int e = beg; e < end; e += 2) {
            int s0 = esrc[e];
            bool has1 = (e + 1 < end);
            int s1 = has1 ? esrc[e + 1] : s0;
            const bf16x8* p0 = (const bf16x8*)(srcbuf + (size_t)s0 * HDIM + kg * 8);
            const bf16x8* p1 = (const bf16x8*)(srcbuf + (size_t)s1 * HDIM + kg * 8);
            bf16x8 v0[4], v1[4];
#pragma unroll
            for (int k0 = 0; k0 < 4; ++k0) { v0[k0] = p0[k0 * 4]; v1[k0] = p1[k0 * 4]; }
#pragma unroll
            for (int k0 = 0; k0 < 4; ++k0) {
                short8 sv = __builtin_bit_cast(short8, v0[k0]);
#pragma unroll
                for (int j = 0; j < 8; ++j) ga[k0][j] += sigpow<SIG>(bf2f((u16)sv[j]));
            }
            if (has1) {
#pragma unroll
                for (int k0 = 0; k0 < 4; ++k0) {
                    short8 sv = __builtin_bit_cast(short8, v1[k0]);
#pragma unroll
                    for (int j = 0; j < 8; ++j) ga[k0][j] += sigpow<SIG>(bf2f((u16)sv[j]));
                }
            }
        }
    }
    bf16x8 afrag[4];
#pragma unroll
    for (int k0 = 0; k0 < 4; ++k0) {
        short8 s;
#pragma unroll
        for (int j = 0; j < 8; ++j) s[j] = (short)f2bf(ga[k0][j]);
        afrag[k0] = __builtin_bit_cast(bf16x8, s);
    }
    __syncthreads();

    f32x4 acc[8];
#pragma unroll
    for (int ct = 0; ct < 8; ++ct) acc[ct] = (f32x4){0.f, 0.f, 0.f, 0.f};
    gemm128(afrag, wls, acc, col, kg);

#pragma unroll
    for (int ct = 0; ct < 8; ++ct)
#pragma unroll
        for (int r = 0; r < 4; ++r) {
            int crow = kg * 4 + r;
            zs[wave][crow][(ct * 16 + col) ^ ((crow & 7) << 3)] = f2bf(sigmoidf_(acc[ct][r]));
        }

    if (MODE == 0) {
#pragma unroll
        for (int it = 0; it < 4; ++it) {
            int cid = it * 64 + lane;
            int r = cid >> 4, c = cid & 15;
            int grow = wrow0 + r;
            if (grow < n) {
                short8 v = *(const short8*)(&zs[wave][r][(c * 8) ^ ((r & 7) << 3)]);
                *(short8*)(outB + (size_t)grow * HDIM + c * 8) = v;
            }
        }
        return;
    }

    __syncthreads();
    stage_w(w1t, wls, tid);
    __syncthreads();

    bf16x8 zfrag[4];
    {
        int zswz = (col & 7) << 3;
#pragma unroll
        for (int k0 = 0; k0 < 4; ++k0)
            zfrag[k0] = *(const bf16x8*)(&zs[wave][col][(k0 * 32 + kg * 8) ^ zswz]);
    }
#pragma unroll
    for (int ct = 0; ct < 8; ++ct) acc[ct] = (f32x4){0.f, 0.f, 0.f, 0.f};
    gemm128(zfrag, wls, acc, col, kg);
#pragma unroll
    for (int ct = 0; ct < 8; ++ct) {
        float b1v = b1[ct * 16 + col];
#pragma unroll
        for (int r = 0; r < 4; ++r) {
            int crow = kg * 4 + r;
            zs[wave][crow][(ct * 16 + col) ^ ((crow & 7) << 3)] = f2bf(siluf_(acc[ct][r] + b1v));
        }
    }
    __syncthreads();
    stage_w(w2t, wls, tid);
    __syncthreads();

    {
        int zswz = (col & 7) << 3;
#pragma unroll
        for (int k0 = 0; k0 < 4; ++k0)
            zfrag[k0] = *(const bf16x8*)(&zs[wave][col][(k0 * 32 + kg * 8) ^ zswz]);
    }
#pragma unroll
    for (int ct = 0; ct < 8; ++ct) acc[ct] = (f32x4){0.f, 0.f, 0.f, 0.f};
    gemm128(zfrag, wls, acc, col, kg);

    pool_acc(acc, b2, batch, p, n, colOff, wrow0, col, kg);
}

// ---------------------------------------------------------------------------
// Rank-0 prepool: y = silu(sig^SIG(h)@W1+b1)@W2+b2, pooled.
// ---------------------------------------------------------------------------
template <int SIG>
__global__ __launch_bounds__(512) void prepool_mfma_kernel(
    const u16* __restrict__ h, const u16* __restrict__ w1t, const u16* __restrict__ w2t,
    const float* __restrict__ b1, const float* __restrict__ b2, const int* __restrict__ batch,
    float* __restrict__ p, int n, int colOff) {
    __shared__ u16 wls[16384];
    __shared__ u16 zs[8][16][128];
    const int tid = threadIdx.x;
    const int wave = tid >> 6, lane = tid & 63;
    const int row0 = blockIdx.x * 128;
    const int col = lane & 15, kg = lane >> 4;
    const int wrow0 = row0 + wave * 16;

    stage_w(w1t, wls, tid);

    const int arow = wrow0 + col;
    const int arowc = arow < n ? arow : (n - 1);
    bf16x8 afrag[4];
    {
        const bf16x8* ap = (const bf16x8*)(h + (size_t)arowc * HDIM + kg * 8);
#pragma unroll
        for (int k0 = 0; k0 < 4; ++k0) afrag[k0] = ap[k0 * 4];
    }
    if (SIG > 0) {
#pragma unroll
        for (int k0 = 0; k0 < 4; ++k0) {
            short8 s = __builtin_bit_cast(short8, afrag[k0]);
#pragma unroll
            for (int j = 0; j < 8; ++j) s[j] = (short)f2bf(sigpow<SIG>(bf2f((u16)s[j])));
            afrag[k0] = __builtin_bit_cast(bf16x8, s);
        }
    }
    __syncthreads();

    f32x4 acc[8];
#pragma unroll
    for (int ct = 0; ct < 8; ++ct) acc[ct] = (f32x4){0.f, 0.f, 0.f, 0.f};
    gemm128(afrag, wls, acc, col, kg);
#pragma unroll
    for (int ct = 0; ct < 8; ++ct) {
        float b1v = b1[ct * 16 + col];
#pragma unroll
        for (int r = 0; r < 4; ++r) {
            int crow = kg * 4 + r;
            zs[wave][crow][(ct * 16 + col) ^ ((crow & 7) << 3)] = f2bf(siluf_(acc[ct][r] + b1v));
        }
    }
    __syncthreads();
    stage_w(w2t, wls, tid);
    __syncthreads();

    bf16x8 zfrag[4];
    {
        int zswz = (col & 7) << 3;
#pragma unroll
        for (int k0 = 0; k0 < 4; ++k0)
            zfrag[k0] = *(const bf16x8*)(&zs[wave][col][(k0 * 32 + kg * 8) ^ zswz]);
    }
#pragma unroll
    for (int ct = 0; ct < 8; ++ct) acc[ct] = (f32x4){0.f, 0.f, 0.f, 0.f};
    gemm128(zfrag, wls, acc, col, kg);

    pool_acc(acc, b2, batch, p, n, colOff, wrow0, col, kg);
}

// ---------------------------------------------------------------------------
__global__ void final_kernel(const float* __restrict__ p, const float* __restrict__ w1,
                             const float* __restrict__ b1, const float* __restrict__ w2,
                             const float* __restrict__ b2, float* __restrict__ out) {
    const int g = blockIdx.x;
    const int c = threadIdx.x;
    const float* pg = p + g * (RANKS * HDIM);
    float acc = b1[c];
    for (int k = 0; k < RANKS * HDIM; ++k) acc = fmaf(pg[k], w1[k * HDIM + c], acc);
    float z = siluf_(acc);
    float v = z * w2[c];
#pragma unroll
    for (int off = 32; off > 0; off >>= 1) v += __shfl_down(v, off, 64);
    __shared__ float red[2];
    if ((c & 63) == 0) red[c >> 6] = v;
    __syncthreads();
    if (c == 0) out[g] = red[0] + red[1] + b2[0];
}

// ---------------------------------------------------------------------------
extern "C" void kernel_launch(void* const* d_in, const int* in_sizes, int n_in,
                              void* d_out, int out_size, void* d_ws, size_t ws_size,
                              hipStream_t stream) {
    const float* x0 = (const float*)d_in[0];
    const float* x1 = (const float*)d_in[1];
    const int* b1_rows = (const int*)d_in[3];
    const int* b1_cols = (const int*)d_in[4];
    const int* b2_rows = (const int*)d_in[5];
    const int* b2_cols = (const int*)d_in[6];
    const int* batch0 = (const int*)d_in[7];
    const int* batch1 = (const int*)d_in[8];
    const int* batch2 = (const int*)d_in[9];
    const float* w_emb = (const float*)d_in[10];
    const float* b_emb = (const float*)d_in[11];
    const float* conv_w = (const float*)d_in[12];
    const float* pre_w1 = (const float*)d_in[13];
    const float* pre_b1 = (const float*)d_in[14];
    const float* pre_w2 = (const float*)d_in[15];
    const float* pre_b2 = (const float*)d_in[16];
    const float* post_w1 = (const float*)d_in[17];
    const float* post_b1 = (const float*)d_in[18];
    const float* post_w2 = (const float*)d_in[19];
    const float* post_b2 = (const float*)d_in[20];

    const int N0 = in_sizes[0] / NIN_;
    const int N1 = in_sizes[1] / NIN_;
    const int N2 = in_sizes[2] / NIN_;
    const int NNZ1 = in_sizes[3];
    const int NNZ2 = in_sizes[5];
    const int L = in_sizes[12] / (2 * HDIM * HDIM);
    const int Gn = out_size;

    // ws: A | As | B | p | wt | wembT | CSR   (~286 MB < 308 MB proven bound)
    u16* A = (u16*)d_ws;
    u16* As = A + (size_t)N0 * HDIM;
    u16* B = As + (size_t)N0 * HDIM;
    float* p = (float*)(B + (size_t)N1 * HDIM);
    u16* wt = (u16*)(p + (size_t)Gn * RANKS * HDIM);
    const u16* wt_conv = wt;                        // [2L][16384]
    const u16* wt_p1 = wt + (size_t)2 * L * 16384;  // [3][16384]
    const u16* wt_p2 = wt_p1 + (size_t)3 * 16384;   // [3][16384]
    u16* wembT = wt + (size_t)(2 * L + 6) * 16384;  // [4096]
    int* ip = (int*)(wembT + 4096);
    int* rowptr1 = ip;  ip += N1 + 1;
    int* rowptr2 = ip;  ip += N2 + 1;
    int* esrc1 = ip;    ip += NNZ1;
    int* esrc2 = ip;    ip += NNZ2;
    int* cntA = ip;     ip += N1;
    int* cntB = ip;     ip += N2;
    int* curA = ip;     ip += N1;
    int* curB = ip;     ip += N2;
    int* bsum = ip;     ip += 2048;

    // 0) weight pre-transforms + CSR builds
    {
        int tot = (2 * L + 6) * 16384;
        wprep_kernel<<<(tot + 255) / 256, 256, 0, stream>>>(conv_w, pre_w1, pre_w2, wt, L);
        wembprep_kernel<<<16, 256, 0, stream>>>(w_emb, wembT);

        zero_kernel<<<1024, 256, 0, stream>>>((u32*)cntA, (long long)(N1 + N2));
        count2_kernel<<<(NNZ1 + NNZ2 + 255) / 256, 256, 0, stream>>>(b1_cols, NNZ1, cntA,
                                                                     b2_cols, NNZ2, cntB);
        int nb1 = (N1 + 1023) / 1024;
        scan1_kernel<<<nb1, 256, 0, stream>>>(cntA, bsum, N1);
        scan2_kernel<<<1, 256, 0, stream>>>(bsum, nb1, rowptr1 + N1);
        scan3_kernel<<<nb1, 256, 0, stream>>>(cntA, bsum, rowptr1, curA, N1);
        int nb2 = (N2 + 1023) / 1024;
        scan1_kernel<<<nb2, 256, 0, stream>>>(cntB, bsum, N2);
        scan2_kernel<<<1, 256, 0, stream>>>(bsum, nb2, rowptr2 + N2);
        scan3_kernel<<<nb2, 256, 0, stream>>>(cntB, bsum, rowptr2, curB, N2);
        fill2_kernel<<<(NNZ1 + NNZ2 + 255) / 256, 256, 0, stream>>>(
            b1_rows, b1_cols, curA, esrc1, NNZ1, b2_rows, b2_cols, curB, esrc2, NNZ2);
    }

    // 1) rank-0 embedding: A = raw embed, As = sigmoid(A)
    embed_mfma_kernel<<<(N0 + 127) / 128, 512, 0, stream>>>(x0, wembT, b_emb, A, As, N0);

    // 2) pooled state buffer
    zero_kernel<<<64, 256, 0, stream>>>((u32*)p, (long long)Gn * RANKS * HDIM);

    if (L >= 2) {
        // MERGED: one CSR1 gather -> {B store, rank-1 prepool -> pool}
        int grid = (N1 + 127) / 128;
        const u16* wc0 = wt_conv + (size_t)((L - 2) * 2 + 0) * 16384;
        const u16* wc1 = wt_conv + (size_t)((L - 1) * 2 + 0) * 16384;
        switch (L - 2) {
            case 0: merged_n1_kernel<0><<<grid, 512, 0, stream>>>(
                        A, As, rowptr1, esrc1, wc0, wc1, wt_p1 + 16384, wt_p2 + 16384,
                        pre_b1 + HDIM, pre_b2 + HDIM, batch1, p, HDIM, B, N1); break;
            case 1: merged_n1_kernel<1><<<grid, 512, 0, stream>>>(
                        A, As, rowptr1, esrc1, wc0, wc1, wt_p1 + 16384, wt_p2 + 16384,
                        pre_b1 + HDIM, pre_b2 + HDIM, batch1, p, HDIM, B, N1); break;
            default: merged_n1_kernel<2><<<grid, 512, 0, stream>>>(
                        A, As, rowptr1, esrc1, wc0, wc1, wt_p1 + 16384, wt_p2 + 16384,
                        pre_b1 + HDIM, pre_b2 + HDIM, batch1, p, HDIM, B, N1); break;
        }
    } else {
        embed_mfma_kernel<<<(N1 + 127) / 128, 512, 0, stream>>>(x1, wembT, b_emb, B, nullptr, N1);
        fused_mfma_kernel<1, 0><<<(N1 + 127) / 128, 512, 0, stream>>>(
            A, rowptr1, esrc1, wt_conv, wt_p1 + 16384, wt_p2 + 16384,
            pre_b1 + HDIM, pre_b2 + HDIM, batch1, p, HDIM, nullptr, N1);
    }

    // rank 2: gather(B over CSR2) -> conv[L-1,1] -> prepool[2] -> pool
    fused_mfma_kernel<1, 0><<<(N2 + 127) / 128, 512, 0, stream>>>(
        B, rowptr2, esrc2, wt_conv + (size_t)((L - 1) * 2 + 1) * 16384,
        wt_p1 + 2 * 16384, wt_p2 + 2 * 16384, pre_b1 + 2 * HDIM, pre_b2 + 2 * HDIM,
        batch2, p, 2 * HDIM, nullptr, N2);

    // rank 0: sig^L(A) = sig^(L-1)(As) -> prepool[0] -> pool
    {
        int grid = (N0 + 127) / 128;
        switch (L - 1) {
            case 0: prepool_mfma_kernel<0><<<grid, 512, 0, stream>>>(
                        As, wt_p1, wt_p2, pre_b1, pre_b2, batch0, p, N0, 0); break;
            case 1: prepool_mfma_kernel<1><<<grid, 512, 0, stream>>>(
                        As, wt_p1, wt_p2, pre_b1, pre_b2, batch0, p, N0, 0); break;
            default: prepool_mfma_kernel<2><<<grid, 512, 0, stream>>>(
                        As, wt_p1, wt_p2, pre_b1, pre_b2, batch0, p, N0, 0); break;
        }
    }

    // 4) head
    final_kernel<<<Gn, HDIM, 0, stream>>>(p, post_w1, post_b1, post_w2, post_b2, (float*)d_out);
}